// Round 2
// baseline (623.066 us; speedup 1.0000x reference)
//
#include <hip/hip_runtime.h>
#include <cstdint>

typedef unsigned short u16;
typedef __attribute__((ext_vector_type(8))) short short8;   // 8 bf16 (4 VGPRs)
typedef __attribute__((ext_vector_type(4))) float floatx4;  // MFMA C/D
typedef __attribute__((ext_vector_type(4))) float f32x4;
typedef __attribute__((ext_vector_type(8))) u16 u16x8;

static constexpr int K_DIM = 4096;
static constexpr int N_DIM = 11008;
static constexpr int NPACK = 1376;  // N/8
static constexpr int GSIZE = 128;
static constexpr int NGRP = 32;     // K/GSIZE

// fp32 -> bf16 round-to-nearest-even (raw bits)
__device__ __forceinline__ u16 f2bf(float f) {
  uint32_t u = __builtin_bit_cast(uint32_t, f);
  u += 0x7FFFu + ((u >> 16) & 1u);
  return (u16)(u >> 16);
}

// async global->LDS, 16B per lane, dest = wave-uniform base + lane*16
__device__ __forceinline__ void async16(const void* g, void* l) {
  __builtin_amdgcn_global_load_lds(
      (const __attribute__((address_space(1))) void*)g,
      (__attribute__((address_space(3))) void*)l, 16, 0, 0);
}

// ---------------------------------------------------------------------------
// x fp32 [M,K] -> bf16 [M,K]; one thread = 8 elements (16B in, 16B out)
__global__ void cvt_x_bf16(const float* __restrict__ x, u16* __restrict__ xb) {
  int t = blockIdx.x * 256 + threadIdx.x;
  const f32x4* xv = (const f32x4*)x;
  f32x4 a = xv[2 * t];
  f32x4 b = xv[2 * t + 1];
  u16x8 o;
  o[0] = f2bf(a[0]); o[1] = f2bf(a[1]); o[2] = f2bf(a[2]); o[3] = f2bf(a[3]);
  o[4] = f2bf(b[0]); o[5] = f2bf(b[1]); o[6] = f2bf(b[2]); o[7] = f2bf(b[3]);
  ((u16x8*)xb)[t] = o;
}

// ---------------------------------------------------------------------------
// qweight [K, N/8] int32 -> Wt [N, K] bf16 (dequantized, TRANSPOSED)
// v2: k-vectorized stores. Each thread owns one n (c=tid>>3, j=tid&7) and
// writes 16 B (8 consecutive k) per store: 16 store-instrs/thread vs 128
// scalar 2B stores. LDS reads: 8 lanes broadcast per address, banks spread
// by the *33 row stride -> conflict-free.
__global__ __launch_bounds__(256) void dequant_wt(
    const int* __restrict__ qw, const int* __restrict__ qz,
    const float* __restrict__ sc, u16* __restrict__ Wt) {
  constexpr int KT = 128, PT = 32, LSTR = PT + 1;
  __shared__ int pk[KT * LSTR];   // 16.5 KB, [k][p] padded
  __shared__ float scs[PT * 8];   // 1 KB
  __shared__ int zs[PT];

  const int tid = threadIdx.x;
  const int p0 = blockIdx.x * PT;   // 43 blocks
  const int k0 = blockIdx.y * KT;   // 32 blocks
  const int g = k0 >> 7;            // KT == GSIZE: one group per tile

#pragma unroll
  for (int i = 0; i < 16; i++) {    // 4096 ints, coalesced (128B rows)
    int idx = tid + i * 256;
    int r = idx >> 5, c = idx & 31;
    pk[r * LSTR + c] = qw[(size_t)(k0 + r) * NPACK + p0 + c];
  }
  if (tid < PT) zs[tid] = qz[g * NPACK + p0 + tid];
  if (tid < PT * 8) scs[tid] = sc[(size_t)g * N_DIM + p0 * 8 + tid];
  __syncthreads();

  const int c = tid >> 3, j = tid & 7;
  const int sh = ((j & 1) << 4) | ((j >> 1) << 2);  // 0,16,4,20,8,24,12,28
  const int zv = (zs[c] >> sh) & 15;
  const float s = scs[c * 8 + j];
  u16* op = Wt + (size_t)(p0 * 8 + tid) * K_DIM + k0;
#pragma unroll
  for (int kc = 0; kc < 16; kc++) {
    u16x8 o;
#pragma unroll
    for (int i = 0; i < 8; i++) {
      int q = pk[(kc * 8 + i) * LSTR + c];
      o[i] = f2bf((float)(((q >> sh) & 15) - zv) * s);
    }
    *(u16x8*)(op + kc * 8) = o;
  }
}

// ---------------------------------------------------------------------------
// C[M,N] = A[M,K] * Bt[N,K]^T + bias ; bf16 in, fp32 out.
// 256x256 tile, BK=64, 512 thr (8 waves 2x4), 128 KiB double-buffered LDS.
// v2 schedule: with strict double-buffering, buf[t+1] is free exactly at the
// gate of tile t (t-1's trailing barrier). Issue tile t+1's staging as EARLY
// as legal: 2 half-tiles at the gate, 1 in ph0, 1 in ph1; ph2/ph3 pure
// compute. Gate waits vmcnt(4) (t+1's first 4 loads stay in flight) -> the
// last-issued load gets ~2.5 phases (~1250cy) to land vs ~1 phase before.
// T2 XOR-swizzle unchanged: linear LDS dest + inverse-swizzled global source
// + swizzled ds_read (kbyte ^= (lm&7)<<4).
__global__ __launch_bounds__(512, 2) void gemm_bf16_256(
    const u16* __restrict__ A, const u16* __restrict__ Bt,
    const float* __restrict__ bias, float* __restrict__ out, int Mb) {
  constexpr int NT = K_DIM / 64;              // 64 K-tiles
  __shared__ __align__(16) u16 lds[65536];    // 128 KB: [2 buf][A 16384 | B 16384]

  const int f = blockIdx.x;
  int mb, nb;
  if ((Mb & 7) == 0) {                        // XCD swizzle: band of h m-tiles/XCD
    int h = Mb >> 3;
    int xcd = f & 7, s = f >> 3;
    mb = xcd * h + (s % h);
    nb = s / h;
  } else {
    mb = f % Mb;
    nb = f / Mb;
  }
  const int m0 = mb * 256, n0 = nb * 256;

  const int tid = threadIdx.x;
  const int wid = tid >> 6, lane = tid & 63;
  const int lm = lane & 15, quad = lane >> 4;
  const int wr = wid >> 2, wc = wid & 3;      // 2x4 wave grid

  // staging source (per-lane, INVERSE-swizzled so linear LDS dest ends up
  // swizzled): thread covers chunk tid (+512h); row = tid>>3, slot = tid&7.
  const int srow = tid >> 3;
  const int skoff = ((tid & 7) ^ (srow & 7)) << 3;  // elements
  const u16* pA = A + (size_t)(m0 + srow) * K_DIM + skoff;
  const u16* pB = Bt + (size_t)(n0 + srow) * K_DIM + skoff;
  const int ldst = wid * 512;                 // wave-uniform element base

  // read-side swizzled k offsets (elements): kbyte = (s*64+quad*16) ^ ((lm&7)<<4)
  const int xsw = (lm & 7) << 4;
  const int ke0 = ((quad * 16) ^ xsw) >> 1;
  const int ke1 = ((64 + quad * 16) ^ xsw) >> 1;
  const int rowAe = (wr * 128 + lm) * 64;
  const int rowBe = 16384 + (wc * 64 + lm) * 64;

  floatx4 acc[8][4] = {};
  short8 av[4], bv[4];

#define ST(bufe_, h_)                                                          \
  do {                                                                         \
    async16(pA + (size_t)(h_) * 64 * K_DIM,                                    \
            &lds[(bufe_) + ldst + (h_) * 4096]);                               \
    async16(pB + (size_t)(h_) * 64 * K_DIM,                                    \
            &lds[(bufe_) + 16384 + ldst + (h_) * 4096]);                       \
  } while (0)

#define LDSA(i_, ke_) (*(const short8*)&lds[bcur + rowAe + (i_) * 1024 + (ke_)])
#define LDSB(j_, ke_) (*(const short8*)&lds[bcur + rowBe + (j_) * 1024 + (ke_)])
#define MFMA16(iofs_)                                                          \
  _Pragma("unroll") for (int i = 0; i < 4; ++i)                                \
  _Pragma("unroll") for (int j = 0; j < 4; ++j)                                \
      acc[(iofs_) + i][j] = __builtin_amdgcn_mfma_f32_16x16x32_bf16(           \
          av[i], bv[j], acc[(iofs_) + i][j], 0, 0, 0);
#define BAR() __builtin_amdgcn_s_barrier()
#define SCHED0() __builtin_amdgcn_sched_barrier(0)

  // prologue: stage tile 0 into buf 0 (8 loads)
  ST(0, 0); ST(0, 1); ST(0, 2); ST(0, 3);
  pA += 64; pB += 64;

#pragma unroll 1
  for (int t = 0; t < NT - 1; ++t) {
    const int bcur = (t & 1) << 15;
    const int bnxt = bcur ^ 32768;

    // gate: buf bnxt is free (t-1's trailing barrier passed). Issue next
    // tile's first 2 half-tiles, then wait for current tile's 8 loads.
    ST(bnxt, 0);
    ST(bnxt, 1);
    asm volatile("s_waitcnt vmcnt(4)" ::: "memory");
    BAR();
    SCHED0();

    // ph0: kstep 0, wave rows 0-63
#pragma unroll
    for (int j = 0; j < 4; ++j) bv[j] = LDSB(j, ke0);
#pragma unroll
    for (int i = 0; i < 4; ++i) av[i] = LDSA(i, ke0);
    ST(bnxt, 2);
    BAR();
    __builtin_amdgcn_s_setprio(1);
    MFMA16(0);
    __builtin_amdgcn_s_setprio(0);
    BAR();

    // ph1: kstep 0, wave rows 64-127
#pragma unroll
    for (int i = 0; i < 4; ++i) av[i] = LDSA(4 + i, ke0);
    ST(bnxt, 3);
    BAR();
    __builtin_amdgcn_s_setprio(1);
    MFMA16(4);
    __builtin_amdgcn_s_setprio(0);
    BAR();

    // ph2: kstep 1, wave rows 0-63 (pure compute)
#pragma unroll
    for (int j = 0; j < 4; ++j) bv[j] = LDSB(j, ke1);
#pragma unroll
    for (int i = 0; i < 4; ++i) av[i] = LDSA(i, ke1);
    BAR();
    __builtin_amdgcn_s_setprio(1);
    MFMA16(0);
    __builtin_amdgcn_s_setprio(0);
    BAR();

    // ph3: kstep 1, wave rows 64-127 (pure compute)
#pragma unroll
    for (int i = 0; i < 4; ++i) av[i] = LDSA(4 + i, ke1);
    BAR();
    __builtin_amdgcn_s_setprio(1);
    MFMA16(4);
    __builtin_amdgcn_s_setprio(0);
    SCHED0();
    BAR();  // end-of-tile: all reads of buf[cur] done before next staging

    pA += 64;
    pB += 64;
  }

  // peeled final tile: drain all loads, no prefetch
  {
    const int bcur = ((NT - 1) & 1) << 15;
    asm volatile("s_waitcnt vmcnt(0)" ::: "memory");
    BAR();
    SCHED0();
#pragma unroll
    for (int j = 0; j < 4; ++j) bv[j] = LDSB(j, ke0);
#pragma unroll
    for (int i = 0; i < 4; ++i) av[i] = LDSA(i, ke0);
    MFMA16(0);
#pragma unroll
    for (int i = 0; i < 4; ++i) av[i] = LDSA(4 + i, ke0);
    MFMA16(4);
#pragma unroll
    for (int j = 0; j < 4; ++j) bv[j] = LDSB(j, ke1);
#pragma unroll
    for (int i = 0; i < 4; ++i) av[i] = LDSA(i, ke1);
    MFMA16(0);
#pragma unroll
    for (int i = 0; i < 4; ++i) av[i] = LDSA(4 + i, ke1);
    MFMA16(4);
  }

  // epilogue: C/D layout col=lane&15, row=quad*4+reg
  const int colb = n0 + wc * 64 + lm;
  const int row0 = m0 + wr * 128 + quad * 4;
#pragma unroll
  for (int j = 0; j < 4; ++j) {
    float bj = bias[colb + j * 16];
#pragma unroll
    for (int i = 0; i < 8; ++i) {
      int r0 = row0 + i * 16;
#pragma unroll
      for (int r = 0; r < 4; ++r)
        out[(size_t)(r0 + r) * N_DIM + colb + j * 16] = acc[i][j][r] + bj;
    }
  }
#undef ST
#undef LDSA
#undef LDSB
#undef MFMA16
#undef BAR
#undef SCHED0
}

// ---------------------------------------------------------------------------
// previous 128x128 gemm kept as fallback for M%256!=0 (but M%128==0)
__global__ __launch_bounds__(256) void gemm_bf16(
    const u16* __restrict__ A, const u16* __restrict__ Bt,
    const float* __restrict__ bias, float* __restrict__ out, int Mb) {
  constexpr int BK = 32;
  __shared__ __align__(16) u16 As[128 * BK];  // 8KB
  __shared__ __align__(16) u16 Bs[128 * BK];  // 8KB

  const int f = blockIdx.x;
  int mb, nb;
  if ((Mb & 7) == 0) {
    int h = Mb >> 3;
    int xcd = f & 7;
    int s = f >> 3;
    mb = xcd * h + (s % h);
    nb = s / h;
  } else {
    mb = f % Mb;
    nb = f / Mb;
  }
  const int m0 = mb * 128;
  const int n0 = nb * 128;

  const int tid = threadIdx.x;
  const int wave = tid >> 6;
  const int lane = tid & 63;
  const int lm = lane & 15;
  const int quad = lane >> 4;
  const int wm = (wave & 1) * 64;
  const int wn = (wave >> 1) * 64;

  const int c0 = tid, c1 = tid + 256;
  const u16* gA0 = A + (size_t)(m0 + (c0 >> 2)) * K_DIM + (c0 & 3) * 8;
  const u16* gA1 = A + (size_t)(m0 + (c1 >> 2)) * K_DIM + (c1 & 3) * 8;
  const u16* gB0 = Bt + (size_t)(n0 + (c0 >> 2)) * K_DIM + (c0 & 3) * 8;
  const u16* gB1 = Bt + (size_t)(n0 + (c1 >> 2)) * K_DIM + (c1 & 3) * 8;
  u16* lA0 = As + (wave * 64) * 8;
  u16* lA1 = As + (256 + wave * 64) * 8;
  u16* lB0 = Bs + (wave * 64) * 8;
  u16* lB1 = Bs + (256 + wave * 64) * 8;

  floatx4 acc[4][4] = {};

  for (int k0i = 0; k0i < K_DIM; k0i += BK) {
    async16(gA0, lA0);
    async16(gA1, lA1);
    async16(gB0, lB0);
    async16(gB1, lB1);
    gA0 += BK; gA1 += BK; gB0 += BK; gB1 += BK;
    __syncthreads();

    short8 af[4], bfr[4];
#pragma unroll
    for (int i = 0; i < 4; i++)
      af[i] = *(const short8*)&As[(wm + i * 16 + lm) * BK + quad * 8];
#pragma unroll
    for (int j = 0; j < 4; j++)
      bfr[j] = *(const short8*)&Bs[(wn + j * 16 + lm) * BK + quad * 8];
#pragma unroll
    for (int i = 0; i < 4; i++)
#pragma unroll
      for (int j = 0; j < 4; j++)
        acc[i][j] = __builtin_amdgcn_mfma_f32_16x16x32_bf16(af[i], bfr[j],
                                                            acc[i][j], 0, 0, 0);
    __syncthreads();
  }

  const int colb = n0 + wn + lm;
#pragma unroll
  for (int j = 0; j < 4; j++) {
    float bj = bias[colb + j * 16];
#pragma unroll
    for (int i = 0; i < 4; i++) {
      int row = m0 + wm + i * 16 + quad * 4;
#pragma unroll
      for (int r = 0; r < 4; r++)
        out[(size_t)(row + r) * N_DIM + colb + j * 16] = acc[i][j][r] + bj;
    }
  }
}

// ---------------------------------------------------------------------------
// fallback (only if workspace too small): 1 thread / output, fp32
__global__ void naive_gemm(const float* __restrict__ x, const int* __restrict__ qw,
                           const int* __restrict__ qz, const float* __restrict__ sc,
                           const float* __restrict__ bias, float* __restrict__ out,
                           int M) {
  long long idx = (long long)blockIdx.x * 256 + threadIdx.x;
  if (idx >= (long long)M * N_DIM) return;
  int m = (int)(idx / N_DIM);
  int n = (int)(idx % N_DIM);
  int p = n >> 3, j = n & 7;
  int sh = ((j & 1) << 4) | ((j >> 1) << 2);
  float acc = 0.f;
  for (int g = 0; g < NGRP; g++) {
    float s = sc[(size_t)g * N_DIM + n];
    int z = (qz[g * NPACK + p] >> sh) & 15;
    float part = 0.f;
    for (int kk = 0; kk < GSIZE; kk++) {
      int k = g * GSIZE + kk;
      int w = ((qw[(size_t)k * NPACK + p] >> sh) & 15) - z;
      part += x[(size_t)m * K_DIM + k] * (float)w;
    }
    acc += part * s;
  }
  out[idx] = acc + bias[n];
}

// ---------------------------------------------------------------------------
extern "C" void kernel_launch(void* const* d_in, const int* in_sizes, int n_in,
                              void* d_out, int out_size, void* d_ws, size_t ws_size,
                              hipStream_t stream) {
  const float* x = (const float*)d_in[0];
  const int* qw = (const int*)d_in[1];
  const int* qz = (const int*)d_in[2];
  const float* sc = (const float*)d_in[3];
  const float* bias = (const float*)d_in[4];
  float* out = (float*)d_out;
  const int M = in_sizes[0] / K_DIM;  // 4096 (B*S)

  size_t xb_bytes = (size_t)M * K_DIM * 2;           // 33.5 MB
  size_t wt_bytes = (size_t)K_DIM * N_DIM * 2;       // 90.2 MB

  if (ws_size >= xb_bytes + wt_bytes && (M % 128) == 0) {
    u16* xb = (u16*)d_ws;
    u16* Wt = (u16*)((char*)d_ws + xb_bytes);
    int cvt_blocks = (M * (K_DIM / 8)) / 256;        // exact: M%128==0
    cvt_x_bf16<<<cvt_blocks, 256, 0, stream>>>(x, xb);
    dequant_wt<<<dim3(NPACK / 32, K_DIM / 128), 256, 0, stream>>>(qw, qz, sc, Wt);
    if ((M % 256) == 0) {
      int Mb = M / 256;
      gemm_bf16_256<<<dim3(Mb * (N_DIM / 256)), 512, 0, stream>>>(xb, Wt, bias,
                                                                  out, Mb);
    } else {
      int Mb = M / 128;
      gemm_bf16<<<dim3(Mb * (N_DIM / 128)), 256, 0, stream>>>(xb, Wt, bias, out,
                                                              Mb);
    }
  } else {
    long long total = (long long)M * N_DIM;
    naive_gemm<<<(int)((total + 255) / 256), 256, 0, stream>>>(x, qw, qz, sc, bias,
                                                               out, M);
  }
}

// Round 3
// 607.751 us; speedup vs baseline: 1.0252x; 1.0252x over previous
//
#include <hip/hip_runtime.h>
#include <cstdint>

typedef unsigned short u16;
typedef __attribute__((ext_vector_type(8))) short short8;     // 8 bf16 (4 VGPRs)
typedef __attribute__((ext_vector_type(4))) float floatx4;
typedef __attribute__((ext_vector_type(16))) float f32x16;    // 32x32 MFMA C/D
typedef __attribute__((ext_vector_type(4))) float f32x4;
typedef __attribute__((ext_vector_type(8))) u16 u16x8;

static constexpr int K_DIM = 4096;
static constexpr int N_DIM = 11008;
static constexpr int NPACK = 1376;  // N/8
static constexpr int GSIZE = 128;
static constexpr int NGRP = 32;     // K/GSIZE

// fp32 -> bf16 round-to-nearest-even (raw bits)
__device__ __forceinline__ u16 f2bf(float f) {
  uint32_t u = __builtin_bit_cast(uint32_t, f);
  u += 0x7FFFu + ((u >> 16) & 1u);
  return (u16)(u >> 16);
}

// async global->LDS, 16B per lane, dest = wave-uniform base + lane*16
__device__ __forceinline__ void async16(const void* g, void* l) {
  __builtin_amdgcn_global_load_lds(
      (const __attribute__((address_space(1))) void*)g,
      (__attribute__((address_space(3))) void*)l, 16, 0, 0);
}

// ---------------------------------------------------------------------------
// x fp32 [M,K] -> bf16 [M,K]; one thread = 8 elements (16B in, 16B out)
__global__ void cvt_x_bf16(const float* __restrict__ x, u16* __restrict__ xb) {
  int t = blockIdx.x * 256 + threadIdx.x;
  const f32x4* xv = (const f32x4*)x;
  f32x4 a = xv[2 * t];
  f32x4 b = xv[2 * t + 1];
  u16x8 o;
  o[0] = f2bf(a[0]); o[1] = f2bf(a[1]); o[2] = f2bf(a[2]); o[3] = f2bf(a[3]);
  o[4] = f2bf(b[0]); o[5] = f2bf(b[1]); o[6] = f2bf(b[2]); o[7] = f2bf(b[3]);
  ((u16x8*)xb)[t] = o;
}

// ---------------------------------------------------------------------------
// qweight [K, N/8] int32 -> Wt [N, K] bf16 (dequantized, TRANSPOSED)
// REVERTED to round-0/1 version: wave-contiguous 128B bf16 stores along k
// (round-2's per-thread 16B stores were 8KB-strided scatter -> regressed).
__global__ __launch_bounds__(256) void dequant_wt(
    const int* __restrict__ qw, const int* __restrict__ qz,
    const float* __restrict__ sc, u16* __restrict__ Wt) {
  constexpr int KT = 128, PT = 32, LSTR = PT + 1;
  __shared__ int pk[KT * LSTR];   // 16.5 KB, [k][p] padded
  __shared__ float scs[PT * 8];   // 1 KB
  __shared__ int zs[PT];

  const int tid = threadIdx.x;
  const int p0 = blockIdx.x * PT;   // 43 blocks
  const int k0 = blockIdx.y * KT;   // 32 blocks
  const int g = k0 >> 7;            // KT == GSIZE: one group per tile

#pragma unroll
  for (int i = 0; i < 16; i++) {    // 4096 ints, coalesced (128B rows)
    int idx = tid + i * 256;
    int r = idx >> 5, c = idx & 31;
    pk[r * LSTR + c] = qw[(size_t)(k0 + r) * NPACK + p0 + c];
  }
  if (tid < PT) zs[tid] = qz[g * NPACK + p0 + tid];
  if (tid < PT * 8) scs[tid] = sc[(size_t)g * N_DIM + p0 * 8 + tid];
  __syncthreads();

  const int wave = tid >> 6, lane = tid & 63;
#pragma unroll 4
  for (int i = 0; i < 64; i++) {
    int nl = wave * 64 + i;         // 0..255 (wave-uniform)
    int c = nl >> 3, j = nl & 7;
    int sh = ((j & 1) << 4) | ((j >> 1) << 2);  // 0,16,4,20,8,24,12,28
    int zv = (zs[c] >> sh) & 15;
    float s = scs[c * 8 + j];
    int q1 = pk[lane * LSTR + c];          // k = lane   (conflict-free)
    int q2 = pk[(lane + 64) * LSTR + c];   // k = lane+64
    size_t ob = (size_t)(p0 * 8 + nl) * K_DIM + k0;
    Wt[ob + lane] = f2bf((float)(((q1 >> sh) & 15) - zv) * s);
    Wt[ob + 64 + lane] = f2bf((float)(((q2 >> sh) & 15) - zv) * s);
  }
}

// ---------------------------------------------------------------------------
// C[M,N] = A[M,K] * Bt[N,K]^T + bias ; bf16 in, fp32 out.
// 256x256 tile, BK=64, 512 thr (8 waves 2x4), 128 KiB double-buffered LDS.
// v3: 32x32x16 MFMA (2382 TF ceiling vs 2075 for 16x16x32; half the MFMA
// instruction count) + 2 phases/K-tile (5 barriers vs 9). ST spread = v1's
// proven placement {gate, ph0 x2, ph1}; gate waits vmcnt(2).
// A-frag: row=lane&31, k=(lane>>5)*8+e. B-frag dual. C/D: col=lane&31,
// row=(reg&3)+8*(reg>>2)+4*(lane>>5)  [HW-verified m74/m101].
// T2 XOR-swizzle unchanged: linear LDS dest (global_load_lds) + inverse-
// swizzled global source + swizzled ds_read (16B chunk c -> c ^ (row&7)).
__global__ __launch_bounds__(512, 2) void gemm_bf16_256(
    const u16* __restrict__ A, const u16* __restrict__ Bt,
    const float* __restrict__ bias, float* __restrict__ out, int Mb) {
  constexpr int NT = K_DIM / 64;              // 64 K-tiles
  __shared__ __align__(16) u16 lds[65536];    // 128 KB: [2 buf][A 16384 | B 16384]

  const int f = blockIdx.x;
  int mb, nb;
  if ((Mb & 7) == 0) {                        // XCD swizzle: band of h m-tiles/XCD
    int h = Mb >> 3;
    int xcd = f & 7, s = f >> 3;
    mb = xcd * h + (s % h);
    nb = s / h;
  } else {
    mb = f % Mb;
    nb = f / Mb;
  }
  const int m0 = mb * 256, n0 = nb * 256;

  const int tid = threadIdx.x;
  const int wid = tid >> 6, lane = tid & 63;
  const int wr = wid >> 2, wc = wid & 3;      // 2x4 wave grid
  const int l31 = lane & 31;
  const int hi = lane >> 5;                   // k-half within fragment
  const int l7 = lane & 7;

  // staging source (per-lane, INVERSE-swizzled so linear LDS dest ends up
  // swizzled): thread covers chunk tid (+512h); row = tid>>3, slot = tid&7.
  const int srow = tid >> 3;
  const int skoff = ((tid & 7) ^ (srow & 7)) << 3;  // elements
  const u16* pA = A + (size_t)(m0 + srow) * K_DIM + skoff;
  const u16* pB = Bt + (size_t)(n0 + srow) * K_DIM + skoff;
  const int ldst = wid * 512;                 // wave-uniform element base

  // read-side swizzled k offsets (elements) for kstep ks (K=16 each):
  // 16B chunk c = ks*2 + hi, swizzled c^(row&7), row&7 == lane&7.
  const int ke0 = ((0 + hi) ^ l7) << 3;
  const int ke1 = ((2 + hi) ^ l7) << 3;
  const int ke2 = ((4 + hi) ^ l7) << 3;
  const int ke3 = ((6 + hi) ^ l7) << 3;
  const int rowAe = (wr * 128 + l31) * 64;
  const int rowBe = 16384 + (wc * 64 + l31) * 64;

  f32x16 acc[4][2] = {};                      // 4 i-subtiles x 2 j-subtiles
  short8 av0[4], av1[4], bv0[2], bv1[2];

#define ST(bufe_, h_)                                                          \
  do {                                                                         \
    async16(pA + (size_t)(h_) * 64 * K_DIM,                                    \
            &lds[(bufe_) + ldst + (h_) * 4096]);                               \
    async16(pB + (size_t)(h_) * 64 * K_DIM,                                    \
            &lds[(bufe_) + 16384 + ldst + (h_) * 4096]);                       \
  } while (0)

#define LDSA(i_, ke_) (*(const short8*)&lds[bcur + rowAe + (i_) * 2048 + (ke_)])
#define LDSB(j_, ke_) (*(const short8*)&lds[bcur + rowBe + (j_) * 2048 + (ke_)])
#define MFMA8(av_, bv_)                                                        \
  _Pragma("unroll") for (int i = 0; i < 4; ++i)                                \
  _Pragma("unroll") for (int j = 0; j < 2; ++j)                                \
      acc[i][j] = __builtin_amdgcn_mfma_f32_32x32x16_bf16(av_[i], bv_[j],      \
                                                          acc[i][j], 0, 0, 0);
#define BAR() __builtin_amdgcn_s_barrier()
#define SCHED0() __builtin_amdgcn_sched_barrier(0)

  // prologue: stage tile 0 into buf 0 (8 loads)
  ST(0, 0); ST(0, 1); ST(0, 2); ST(0, 3);
  pA += 64; pB += 64;

#pragma unroll 1
  for (int t = 0; t < NT - 1; ++t) {
    const int bcur = (t & 1) << 15;
    const int bnxt = bcur ^ 32768;

    // gate: issue next tile's half-tile 0, wait for current tile's 8 loads
    ST(bnxt, 0);
    asm volatile("s_waitcnt vmcnt(2)" ::: "memory");
    BAR();
    SCHED0();

    // ph0: ksteps 0,1
#pragma unroll
    for (int j = 0; j < 2; ++j) bv0[j] = LDSB(j, ke0);
#pragma unroll
    for (int i = 0; i < 4; ++i) av0[i] = LDSA(i, ke0);
#pragma unroll
    for (int j = 0; j < 2; ++j) bv1[j] = LDSB(j, ke1);
#pragma unroll
    for (int i = 0; i < 4; ++i) av1[i] = LDSA(i, ke1);
    ST(bnxt, 1);
    ST(bnxt, 2);
    BAR();
    __builtin_amdgcn_s_setprio(1);
    MFMA8(av0, bv0);
    MFMA8(av1, bv1);
    __builtin_amdgcn_s_setprio(0);
    BAR();

    // ph1: ksteps 2,3
#pragma unroll
    for (int j = 0; j < 2; ++j) bv0[j] = LDSB(j, ke2);
#pragma unroll
    for (int i = 0; i < 4; ++i) av0[i] = LDSA(i, ke2);
#pragma unroll
    for (int j = 0; j < 2; ++j) bv1[j] = LDSB(j, ke3);
#pragma unroll
    for (int i = 0; i < 4; ++i) av1[i] = LDSA(i, ke3);
    ST(bnxt, 3);
    BAR();
    __builtin_amdgcn_s_setprio(1);
    MFMA8(av0, bv0);
    MFMA8(av1, bv1);
    __builtin_amdgcn_s_setprio(0);
    SCHED0();
    BAR();  // end-of-tile: all reads of buf[cur] done before next staging

    pA += 64;
    pB += 64;
  }

  // peeled final tile: drain all loads, no prefetch
  {
    const int bcur = ((NT - 1) & 1) << 15;
    asm volatile("s_waitcnt vmcnt(0)" ::: "memory");
    BAR();
    SCHED0();
#pragma unroll
    for (int j = 0; j < 2; ++j) bv0[j] = LDSB(j, ke0);
#pragma unroll
    for (int i = 0; i < 4; ++i) av0[i] = LDSA(i, ke0);
#pragma unroll
    for (int j = 0; j < 2; ++j) bv1[j] = LDSB(j, ke1);
#pragma unroll
    for (int i = 0; i < 4; ++i) av1[i] = LDSA(i, ke1);
    MFMA8(av0, bv0);
    MFMA8(av1, bv1);
#pragma unroll
    for (int j = 0; j < 2; ++j) bv0[j] = LDSB(j, ke2);
#pragma unroll
    for (int i = 0; i < 4; ++i) av0[i] = LDSA(i, ke2);
#pragma unroll
    for (int j = 0; j < 2; ++j) bv1[j] = LDSB(j, ke3);
#pragma unroll
    for (int i = 0; i < 4; ++i) av1[i] = LDSA(i, ke3);
    MFMA8(av0, bv0);
    MFMA8(av1, bv1);
  }

  // epilogue: C/D 32x32 layout: col=lane&31, row=(reg&3)+8*(reg>>2)+4*hi
#pragma unroll
  for (int j = 0; j < 2; ++j) {
    int col = n0 + wc * 64 + j * 32 + l31;
    float bj = bias[col];
#pragma unroll
    for (int i = 0; i < 4; ++i) {
      int rb = m0 + wr * 128 + i * 32 + hi * 4;
#pragma unroll
      for (int reg = 0; reg < 16; ++reg) {
        int row = rb + (reg & 3) + 8 * (reg >> 2);
        out[(size_t)row * N_DIM + col] = acc[i][j][reg] + bj;
      }
    }
  }
#undef ST
#undef LDSA
#undef LDSB
#undef MFMA8
#undef BAR
#undef SCHED0
}

// ---------------------------------------------------------------------------
// previous 128x128 gemm kept as fallback for M%256!=0 (but M%128==0)
__global__ __launch_bounds__(256) void gemm_bf16(
    const u16* __restrict__ A, const u16* __restrict__ Bt,
    const float* __restrict__ bias, float* __restrict__ out, int Mb) {
  constexpr int BK = 32;
  __shared__ __align__(16) u16 As[128 * BK];  // 8KB
  __shared__ __align__(16) u16 Bs[128 * BK];  // 8KB

  const int f = blockIdx.x;
  int mb, nb;
  if ((Mb & 7) == 0) {
    int h = Mb >> 3;
    int xcd = f & 7;
    int s = f >> 3;
    mb = xcd * h + (s % h);
    nb = s / h;
  } else {
    mb = f % Mb;
    nb = f / Mb;
  }
  const int m0 = mb * 128;
  const int n0 = nb * 128;

  const int tid = threadIdx.x;
  const int wave = tid >> 6;
  const int lane = tid & 63;
  const int lm = lane & 15;
  const int quad = lane >> 4;
  const int wm = (wave & 1) * 64;
  const int wn = (wave >> 1) * 64;

  const int c0 = tid, c1 = tid + 256;
  const u16* gA0 = A + (size_t)(m0 + (c0 >> 2)) * K_DIM + (c0 & 3) * 8;
  const u16* gA1 = A + (size_t)(m0 + (c1 >> 2)) * K_DIM + (c1 & 3) * 8;
  const u16* gB0 = Bt + (size_t)(n0 + (c0 >> 2)) * K_DIM + (c0 & 3) * 8;
  const u16* gB1 = Bt + (size_t)(n0 + (c1 >> 2)) * K_DIM + (c1 & 3) * 8;
  u16* lA0 = As + (wave * 64) * 8;
  u16* lA1 = As + (256 + wave * 64) * 8;
  u16* lB0 = Bs + (wave * 64) * 8;
  u16* lB1 = Bs + (256 + wave * 64) * 8;

  floatx4 acc[4][4] = {};

  for (int k0i = 0; k0i < K_DIM; k0i += BK) {
    async16(gA0, lA0);
    async16(gA1, lA1);
    async16(gB0, lB0);
    async16(gB1, lB1);
    gA0 += BK; gA1 += BK; gB0 += BK; gB1 += BK;
    __syncthreads();

    short8 af[4], bfr[4];
#pragma unroll
    for (int i = 0; i < 4; i++)
      af[i] = *(const short8*)&As[(wm + i * 16 + lm) * BK + quad * 8];
#pragma unroll
    for (int j = 0; j < 4; j++)
      bfr[j] = *(const short8*)&Bs[(wn + j * 16 + lm) * BK + quad * 8];
#pragma unroll
    for (int i = 0; i < 4; i++)
#pragma unroll
      for (int j = 0; j < 4; j++)
        acc[i][j] = __builtin_amdgcn_mfma_f32_16x16x32_bf16(af[i], bfr[j],
                                                            acc[i][j], 0, 0, 0);
    __syncthreads();
  }

  const int colb = n0 + wn + lm;
#pragma unroll
  for (int j = 0; j < 4; j++) {
    float bj = bias[colb + j * 16];
#pragma unroll
    for (int i = 0; i < 4; i++) {
      int row = m0 + wm + i * 16 + quad * 4;
#pragma unroll
      for (int r = 0; r < 4; r++)
        out[(size_t)(row + r) * N_DIM + colb + j * 16] = acc[i][j][r] + bj;
    }
  }
}

// ---------------------------------------------------------------------------
// fallback (only if workspace too small): 1 thread / output, fp32
__global__ void naive_gemm(const float* __restrict__ x, const int* __restrict__ qw,
                           const int* __restrict__ qz, const float* __restrict__ sc,
                           const float* __restrict__ bias, float* __restrict__ out,
                           int M) {
  long long idx = (long long)blockIdx.x * 256 + threadIdx.x;
  if (idx >= (long long)M * N_DIM) return;
  int m = (int)(idx / N_DIM);
  int n = (int)(idx % N_DIM);
  int p = n >> 3, j = n & 7;
  int sh = ((j & 1) << 4) | ((j >> 1) << 2);
  float acc = 0.f;
  for (int g = 0; g < NGRP; g++) {
    float s = sc[(size_t)g * N_DIM + n];
    int z = (qz[g * NPACK + p] >> sh) & 15;
    float part = 0.f;
    for (int kk = 0; kk < GSIZE; kk++) {
      int k = g * GSIZE + kk;
      int w = ((qw[(size_t)k * NPACK + p] >> sh) & 15) - z;
      part += x[(size_t)m * K_DIM + k] * (float)w;
    }
    acc += part * s;
  }
  out[idx] = acc + bias[n];
}

// ---------------------------------------------------------------------------
extern "C" void kernel_launch(void* const* d_in, const int* in_sizes, int n_in,
                              void* d_out, int out_size, void* d_ws, size_t ws_size,
                              hipStream_t stream) {
  const float* x = (const float*)d_in[0];
  const int* qw = (const int*)d_in[1];
  const int* qz = (const int*)d_in[2];
  const float* sc = (const float*)d_in[3];
  const float* bias = (const float*)d_in[4];
  float* out = (float*)d_out;
  const int M = in_sizes[0] / K_DIM;  // 4096 (B*S)

  size_t xb_bytes = (size_t)M * K_DIM * 2;           // 33.5 MB
  size_t wt_bytes = (size_t)K_DIM * N_DIM * 2;       // 90.2 MB

  if (ws_size >= xb_bytes + wt_bytes && (M % 128) == 0) {
    u16* xb = (u16*)d_ws;
    u16* Wt = (u16*)((char*)d_ws + xb_bytes);
    int cvt_blocks = (M * (K_DIM / 8)) / 256;        // exact: M%128==0
    cvt_x_bf16<<<cvt_blocks, 256, 0, stream>>>(x, xb);
    dequant_wt<<<dim3(NPACK / 32, K_DIM / 128), 256, 0, stream>>>(qw, qz, sc, Wt);
    if ((M % 256) == 0) {
      int Mb = M / 256;
      gemm_bf16_256<<<dim3(Mb * (N_DIM / 256)), 512, 0, stream>>>(xb, Wt, bias,
                                                                  out, Mb);
    } else {
      int Mb = M / 128;
      gemm_bf16<<<dim3(Mb * (N_DIM / 128)), 256, 0, stream>>>(xb, Wt, bias, out,
                                                              Mb);
    }
  } else {
    long long total = (long long)M * N_DIM;
    naive_gemm<<<(int)((total + 255) / 256), 256, 0, stream>>>(x, qw, qz, sc, bias,
                                                               out, M);
  }
}

// Round 4
// 577.937 us; speedup vs baseline: 1.0781x; 1.0516x over previous
//
#include <hip/hip_runtime.h>
#include <cstdint>

typedef unsigned short u16;
typedef __attribute__((ext_vector_type(8))) short short8;   // 8 bf16 (4 VGPRs)
typedef __attribute__((ext_vector_type(4))) float floatx4;  // MFMA C/D
typedef __attribute__((ext_vector_type(4))) float f32x4;
typedef __attribute__((ext_vector_type(8))) u16 u16x8;

static constexpr int K_DIM = 4096;
static constexpr int N_DIM = 11008;
static constexpr int NPACK = 1376;  // N/8
static constexpr int GSIZE = 128;
static constexpr int NGRP = 32;     // K/GSIZE

// fp32 -> bf16 round-to-nearest-even (raw bits)
__device__ __forceinline__ u16 f2bf(float f) {
  uint32_t u = __builtin_bit_cast(uint32_t, f);
  u += 0x7FFFu + ((u >> 16) & 1u);
  return (u16)(u >> 16);
}

// async global->LDS, 16B per lane, dest = wave-uniform base + lane*16
__device__ __forceinline__ void async16(const void* g, void* l) {
  __builtin_amdgcn_global_load_lds(
      (const __attribute__((address_space(1))) void*)g,
      (__attribute__((address_space(3))) void*)l, 16, 0, 0);
}

// ---------------------------------------------------------------------------
// x fp32 [M,K] -> bf16 [M,K]; one thread = 8 elements (16B in, 16B out)
__global__ void cvt_x_bf16(const float* __restrict__ x, u16* __restrict__ xb) {
  int t = blockIdx.x * 256 + threadIdx.x;
  const f32x4* xv = (const f32x4*)x;
  f32x4 a = xv[2 * t];
  f32x4 b = xv[2 * t + 1];
  u16x8 o;
  o[0] = f2bf(a[0]); o[1] = f2bf(a[1]); o[2] = f2bf(a[2]); o[3] = f2bf(a[3]);
  o[4] = f2bf(b[0]); o[5] = f2bf(b[1]); o[6] = f2bf(b[2]); o[7] = f2bf(b[3]);
  ((u16x8*)xb)[t] = o;
}

// ---------------------------------------------------------------------------
// qweight [K, N/8] int32 -> Wt [N, K] bf16 (dequantized, TRANSPOSED)
// v3 stores: lane l -> (n = c*8 + (l>>3), k = kk*64 + (l&7)*8); each lane
// writes one u16x8 (16B). Per 8-lane group: 128B contiguous (full 64B lines,
// no write amplification — R2's mistake); per wave-store: 8 segments, 1KB.
// 16 store-instrs/thread-block-row vs 128 scalar 2B stores in v0.
// LDS reads: 8 lanes broadcast per address; same-bank aliasing is 2-way
// ((l&7) vs (l&7)+4 differ by 1056 words = 0 mod 32) -> free per m136.
__global__ __launch_bounds__(256) void dequant_wt(
    const int* __restrict__ qw, const int* __restrict__ qz,
    const float* __restrict__ sc, u16* __restrict__ Wt) {
  constexpr int KT = 128, PT = 32, LSTR = PT + 1;
  __shared__ int pk[KT * LSTR];   // 16.5 KB, [k][p] padded
  __shared__ float scs[PT * 8];   // 1 KB
  __shared__ int zs[PT];

  const int tid = threadIdx.x;
  const int p0 = blockIdx.x * PT;   // 43 blocks
  const int k0 = blockIdx.y * KT;   // 32 blocks
  const int g = k0 >> 7;            // KT == GSIZE: one group per tile

#pragma unroll
  for (int i = 0; i < 16; i++) {    // 4096 ints, coalesced (128B rows)
    int idx = tid + i * 256;
    int r = idx >> 5, c = idx & 31;
    pk[r * LSTR + c] = qw[(size_t)(k0 + r) * NPACK + p0 + c];
  }
  if (tid < PT) zs[tid] = qz[g * NPACK + p0 + tid];
  if (tid < PT * 8) scs[tid] = sc[(size_t)g * N_DIM + p0 * 8 + tid];
  __syncthreads();

  const int wave = tid >> 6, lane = tid & 63;
  const int j = lane >> 3;                       // n-position in packed int
  const int kb = (lane & 7) * 8;                 // k-offset of this lane's 8k
  const int sh = ((j & 1) << 4) | ((j >> 1) << 2);  // 0,16,4,20,8,24,12,28

#pragma unroll 2
  for (int ci = 0; ci < 8; ci++) {
    const int c = wave * 8 + ci;                 // packed col 0..31
    const int zv = (zs[c] >> sh) & 15;
    const float s = scs[c * 8 + j];
    u16* op = Wt + (size_t)(p0 * 8 + c * 8 + j) * K_DIM + k0 + kb;
#pragma unroll
    for (int kk = 0; kk < 2; kk++) {
      const int kbase = kk * 64 + kb;
      u16x8 o;
#pragma unroll
      for (int e = 0; e < 8; e++) {
        int q = pk[(kbase + e) * LSTR + c];
        o[e] = f2bf((float)(((q >> sh) & 15) - zv) * s);
      }
      *(u16x8*)(op + kk * 64) = o;
    }
  }
}

// ---------------------------------------------------------------------------
// C[M,N] = A[M,K] * Bt[N,K]^T + bias ; bf16 in, fp32 out.
// EXACT revert to the measured-best schedule (357us, MfmaUtil 46, conflicts 0):
// 256x256 tile, BK=64, 512 thr (8 waves 2x4), 128 KiB double-buffered LDS,
// 16x16x32 MFMA, 4 phases/K-tile, ST spread {gate,ph0,ph1,ph2}, gate vmcnt(2).
// (R2: deeper prefetch vmcnt(4) regressed; R3: 32x32x16 MFMA regressed with
//  3.4e7 bank conflicts ~= the +56us — both reverted.)
__global__ __launch_bounds__(512, 2) void gemm_bf16_256(
    const u16* __restrict__ A, const u16* __restrict__ Bt,
    const float* __restrict__ bias, float* __restrict__ out, int Mb) {
  constexpr int NT = K_DIM / 64;              // 64 K-tiles
  __shared__ __align__(16) u16 lds[65536];    // 128 KB: [2 buf][A 16384 | B 16384]

  const int f = blockIdx.x;
  int mb, nb;
  if ((Mb & 7) == 0) {                        // XCD swizzle: band of h m-tiles/XCD
    int h = Mb >> 3;
    int xcd = f & 7, s = f >> 3;
    mb = xcd * h + (s % h);
    nb = s / h;
  } else {
    mb = f % Mb;
    nb = f / Mb;
  }
  const int m0 = mb * 256, n0 = nb * 256;

  const int tid = threadIdx.x;
  const int wid = tid >> 6, lane = tid & 63;
  const int lm = lane & 15, quad = lane >> 4;
  const int wr = wid >> 2, wc = wid & 3;      // 2x4 wave grid

  // staging source (per-lane, INVERSE-swizzled so linear LDS dest ends up
  // swizzled): thread covers chunk tid (+512h); row = tid>>3, slot = tid&7.
  const int srow = tid >> 3;
  const int skoff = ((tid & 7) ^ (srow & 7)) << 3;  // elements
  const u16* pA = A + (size_t)(m0 + srow) * K_DIM + skoff;
  const u16* pB = Bt + (size_t)(n0 + srow) * K_DIM + skoff;
  const int ldst = wid * 512;                 // wave-uniform element base

  // read-side swizzled k offsets (elements): kbyte = (s*64+quad*16) ^ ((lm&7)<<4)
  const int xsw = (lm & 7) << 4;
  const int ke0 = ((quad * 16) ^ xsw) >> 1;
  const int ke1 = ((64 + quad * 16) ^ xsw) >> 1;
  const int rowAe = (wr * 128 + lm) * 64;
  const int rowBe = 16384 + (wc * 64 + lm) * 64;

  floatx4 acc[8][4] = {};
  short8 av[4], bv[4];

#define ST(bufe_, h_)                                                          \
  do {                                                                         \
    async16(pA + (size_t)(h_) * 64 * K_DIM,                                    \
            &lds[(bufe_) + ldst + (h_) * 4096]);                               \
    async16(pB + (size_t)(h_) * 64 * K_DIM,                                    \
            &lds[(bufe_) + 16384 + ldst + (h_) * 4096]);                       \
  } while (0)

#define LDSA(i_, ke_) (*(const short8*)&lds[bcur + rowAe + (i_) * 1024 + (ke_)])
#define LDSB(j_, ke_) (*(const short8*)&lds[bcur + rowBe + (j_) * 1024 + (ke_)])
#define MFMA16(iofs_)                                                          \
  _Pragma("unroll") for (int i = 0; i < 4; ++i)                                \
  _Pragma("unroll") for (int j = 0; j < 4; ++j)                                \
      acc[(iofs_) + i][j] = __builtin_amdgcn_mfma_f32_16x16x32_bf16(           \
          av[i], bv[j], acc[(iofs_) + i][j], 0, 0, 0);
#define BAR() __builtin_amdgcn_s_barrier()
#define SCHED0() __builtin_amdgcn_sched_barrier(0)

  // prologue: stage tile 0 into buf 0 (8 loads)
  ST(0, 0); ST(0, 1); ST(0, 2); ST(0, 3);
  pA += 64; pB += 64;

#pragma unroll 1
  for (int t = 0; t < NT - 1; ++t) {
    const int bcur = (t & 1) << 15;
    const int bnxt = bcur ^ 32768;

    // gate: issue next tile's half-tile 0, wait for current tile's 8 loads
    ST(bnxt, 0);
    asm volatile("s_waitcnt vmcnt(2)" ::: "memory");
    BAR();
    SCHED0();

    // ph0: kstep 0, wave rows 0-63
#pragma unroll
    for (int j = 0; j < 4; ++j) bv[j] = LDSB(j, ke0);
#pragma unroll
    for (int i = 0; i < 4; ++i) av[i] = LDSA(i, ke0);
    ST(bnxt, 1);
    BAR();
    __builtin_amdgcn_s_setprio(1);
    MFMA16(0);
    __builtin_amdgcn_s_setprio(0);
    BAR();

    // ph1: kstep 0, wave rows 64-127
#pragma unroll
    for (int i = 0; i < 4; ++i) av[i] = LDSA(4 + i, ke0);
    ST(bnxt, 2);
    BAR();
    __builtin_amdgcn_s_setprio(1);
    MFMA16(4);
    __builtin_amdgcn_s_setprio(0);
    BAR();

    // ph2: kstep 1, wave rows 0-63
#pragma unroll
    for (int j = 0; j < 4; ++j) bv[j] = LDSB(j, ke1);
#pragma unroll
    for (int i = 0; i < 4; ++i) av[i] = LDSA(i, ke1);
    ST(bnxt, 3);
    BAR();
    __builtin_amdgcn_s_setprio(1);
    MFMA16(0);
    __builtin_amdgcn_s_setprio(0);
    BAR();

    // ph3: kstep 1, wave rows 64-127
#pragma unroll
    for (int i = 0; i < 4; ++i) av[i] = LDSA(4 + i, ke1);
    BAR();
    __builtin_amdgcn_s_setprio(1);
    MFMA16(4);
    __builtin_amdgcn_s_setprio(0);
    SCHED0();
    BAR();  // end-of-tile: all reads of buf[cur] done before next staging

    pA += 64;
    pB += 64;
  }

  // peeled final tile: drain all loads, no prefetch
  {
    const int bcur = ((NT - 1) & 1) << 15;
    asm volatile("s_waitcnt vmcnt(0)" ::: "memory");
    BAR();
    SCHED0();
#pragma unroll
    for (int j = 0; j < 4; ++j) bv[j] = LDSB(j, ke0);
#pragma unroll
    for (int i = 0; i < 4; ++i) av[i] = LDSA(i, ke0);
    MFMA16(0);
#pragma unroll
    for (int i = 0; i < 4; ++i) av[i] = LDSA(4 + i, ke0);
    MFMA16(4);
#pragma unroll
    for (int j = 0; j < 4; ++j) bv[j] = LDSB(j, ke1);
#pragma unroll
    for (int i = 0; i < 4; ++i) av[i] = LDSA(i, ke1);
    MFMA16(0);
#pragma unroll
    for (int i = 0; i < 4; ++i) av[i] = LDSA(4 + i, ke1);
    MFMA16(4);
  }

  // epilogue: C/D layout col=lane&15, row=quad*4+reg
  const int colb = n0 + wc * 64 + lm;
  const int row0 = m0 + wr * 128 + quad * 4;
#pragma unroll
  for (int j = 0; j < 4; ++j) {
    float bj = bias[colb + j * 16];
#pragma unroll
    for (int i = 0; i < 8; ++i) {
      int r0 = row0 + i * 16;
#pragma unroll
      for (int r = 0; r < 4; ++r)
        out[(size_t)(r0 + r) * N_DIM + colb + j * 16] = acc[i][j][r] + bj;
    }
  }
#undef ST
#undef LDSA
#undef LDSB
#undef MFMA16
#undef BAR
#undef SCHED0
}

// ---------------------------------------------------------------------------
// previous 128x128 gemm kept as fallback for M%256!=0 (but M%128==0)
__global__ __launch_bounds__(256) void gemm_bf16(
    const u16* __restrict__ A, const u16* __restrict__ Bt,
    const float* __restrict__ bias, float* __restrict__ out, int Mb) {
  constexpr int BK = 32;
  __shared__ __align__(16) u16 As[128 * BK];  // 8KB
  __shared__ __align__(16) u16 Bs[128 * BK];  // 8KB

  const int f = blockIdx.x;
  int mb, nb;
  if ((Mb & 7) == 0) {
    int h = Mb >> 3;
    int xcd = f & 7;
    int s = f >> 3;
    mb = xcd * h + (s % h);
    nb = s / h;
  } else {
    mb = f % Mb;
    nb = f / Mb;
  }
  const int m0 = mb * 128;
  const int n0 = nb * 128;

  const int tid = threadIdx.x;
  const int wave = tid >> 6;
  const int lane = tid & 63;
  const int lm = lane & 15;
  const int quad = lane >> 4;
  const int wm = (wave & 1) * 64;
  const int wn = (wave >> 1) * 64;

  const int c0 = tid, c1 = tid + 256;
  const u16* gA0 = A + (size_t)(m0 + (c0 >> 2)) * K_DIM + (c0 & 3) * 8;
  const u16* gA1 = A + (size_t)(m0 + (c1 >> 2)) * K_DIM + (c1 & 3) * 8;
  const u16* gB0 = Bt + (size_t)(n0 + (c0 >> 2)) * K_DIM + (c0 & 3) * 8;
  const u16* gB1 = Bt + (size_t)(n0 + (c1 >> 2)) * K_DIM + (c1 & 3) * 8;
  u16* lA0 = As + (wave * 64) * 8;
  u16* lA1 = As + (256 + wave * 64) * 8;
  u16* lB0 = Bs + (wave * 64) * 8;
  u16* lB1 = Bs + (256 + wave * 64) * 8;

  floatx4 acc[4][4] = {};

  for (int k0i = 0; k0i < K_DIM; k0i += BK) {
    async16(gA0, lA0);
    async16(gA1, lA1);
    async16(gB0, lB0);
    async16(gB1, lB1);
    gA0 += BK; gA1 += BK; gB0 += BK; gB1 += BK;
    __syncthreads();

    short8 af[4], bfr[4];
#pragma unroll
    for (int i = 0; i < 4; i++)
      af[i] = *(const short8*)&As[(wm + i * 16 + lm) * BK + quad * 8];
#pragma unroll
    for (int j = 0; j < 4; j++)
      bfr[j] = *(const short8*)&Bs[(wn + j * 16 + lm) * BK + quad * 8];
#pragma unroll
    for (int i = 0; i < 4; i++)
#pragma unroll
      for (int j = 0; j < 4; j++)
        acc[i][j] = __builtin_amdgcn_mfma_f32_16x16x32_bf16(af[i], bfr[j],
                                                            acc[i][j], 0, 0, 0);
    __syncthreads();
  }

  const int colb = n0 + wn + lm;
#pragma unroll
  for (int j = 0; j < 4; j++) {
    float bj = bias[colb + j * 16];
#pragma unroll
    for (int i = 0; i < 4; i++) {
      int row = m0 + wm + i * 16 + quad * 4;
#pragma unroll
      for (int r = 0; r < 4; r++)
        out[(size_t)(row + r) * N_DIM + colb + j * 16] = acc[i][j][r] + bj;
    }
  }
}

// ---------------------------------------------------------------------------
// fallback (only if workspace too small): 1 thread / output, fp32
__global__ void naive_gemm(const float* __restrict__ x, const int* __restrict__ qw,
                           const int* __restrict__ qz, const float* __restrict__ sc,
                           const float* __restrict__ bias, float* __restrict__ out,
                           int M) {
  long long idx = (long long)blockIdx.x * 256 + threadIdx.x;
  if (idx >= (long long)M * N_DIM) return;
  int m = (int)(idx / N_DIM);
  int n = (int)(idx % N_DIM);
  int p = n >> 3, j = n & 7;
  int sh = ((j & 1) << 4) | ((j >> 1) << 2);
  float acc = 0.f;
  for (int g = 0; g < NGRP; g++) {
    float s = sc[(size_t)g * N_DIM + n];
    int z = (qz[g * NPACK + p] >> sh) & 15;
    float part = 0.f;
    for (int kk = 0; kk < GSIZE; kk++) {
      int k = g * GSIZE + kk;
      int w = ((qw[(size_t)k * NPACK + p] >> sh) & 15) - z;
      part += x[(size_t)m * K_DIM + k] * (float)w;
    }
    acc += part * s;
  }
  out[idx] = acc + bias[n];
}

// ---------------------------------------------------------------------------
extern "C" void kernel_launch(void* const* d_in, const int* in_sizes, int n_in,
                              void* d_out, int out_size, void* d_ws, size_t ws_size,
                              hipStream_t stream) {
  const float* x = (const float*)d_in[0];
  const int* qw = (const int*)d_in[1];
  const int* qz = (const int*)d_in[2];
  const float* sc = (const float*)d_in[3];
  const float* bias = (const float*)d_in[4];
  float* out = (float*)d_out;
  const int M = in_sizes[0] / K_DIM;  // 4096 (B*S)

  size_t xb_bytes = (size_t)M * K_DIM * 2;           // 33.5 MB
  size_t wt_bytes = (size_t)K_DIM * N_DIM * 2;       // 90.2 MB

  if (ws_size >= xb_bytes + wt_bytes && (M % 128) == 0) {
    u16* xb = (u16*)d_ws;
    u16* Wt = (u16*)((char*)d_ws + xb_bytes);
    int cvt_blocks = (M * (K_DIM / 8)) / 256;        // exact: M%128==0
    cvt_x_bf16<<<cvt_blocks, 256, 0, stream>>>(x, xb);
    dequant_wt<<<dim3(NPACK / 32, K_DIM / 128), 256, 0, stream>>>(qw, qz, sc, Wt);
    if ((M % 256) == 0) {
      int Mb = M / 256;
      gemm_bf16_256<<<dim3(Mb * (N_DIM / 256)), 512, 0, stream>>>(xb, Wt, bias,
                                                                  out, Mb);
    } else {
      int Mb = M / 128;
      gemm_bf16<<<dim3(Mb * (N_DIM / 128)), 256, 0, stream>>>(xb, Wt, bias, out,
                                                              Mb);
    }
  } else {
    long long total = (long long)M * N_DIM;
    naive_gemm<<<(int)((total + 255) / 256), 256, 0, stream>>>(x, qw, qz, sc, bias,
                                                               out, M);
  }
}